// Round 1
// baseline (722.424 us; speedup 1.0000x reference)
//
#include <hip/hip_runtime.h>

typedef unsigned short u16;
typedef unsigned int u32;
typedef float f32x4 __attribute__((ext_vector_type(4)));
typedef __bf16 bf16x8 __attribute__((ext_vector_type(8)));

#define MFMA16(a, b, c) __builtin_amdgcn_mfma_f32_16x16x32_bf16(a, b, c, 0, 0, 0)

__device__ __forceinline__ u16 f2b(float f) {
    u32 u = __builtin_bit_cast(u32, f);
    u += 0x7fffu + ((u >> 16) & 1u);   // round-to-nearest-even
    return (u16)(u >> 16);
}

// ---------------- weight transpose + f32->bf16 convert ----------------
// W [1024][1024] f32 row-major -> WT [N][K] bf16 (WT[n][k] = W[k][n])
__global__ __launch_bounds__(256) void tcvt_k(const float* __restrict__ Wm, u16* __restrict__ WT) {
    __shared__ float t[32][33];
    int bx = blockIdx.x, by = blockIdx.y;
    int tx = threadIdx.x, ty = threadIdx.y;   // (32,8)
#pragma unroll
    for (int j = 0; j < 32; j += 8)
        t[ty + j][tx] = Wm[(size_t)(by * 32 + ty + j) * 1024 + bx * 32 + tx];
    __syncthreads();
#pragma unroll
    for (int j = 0; j < 32; j += 8)
        WT[(size_t)(bx * 32 + ty + j) * 1024 + by * 32 + tx] = f2b(t[tx][ty + j]);
}

// ---------------- fused LayerNorm ----------------
// MODE bit0: x = in1 + in2 ; bit1: write f32 out (plus bit3: += post) ; bit2: write bf16 out
template <int MODE>
__global__ __launch_bounds__(256) void ln_k(const float* __restrict__ in1, const float* __restrict__ in2,
                                            const float* __restrict__ gg, const float* __restrict__ bb,
                                            const float* __restrict__ post,
                                            float* __restrict__ of, u16* __restrict__ ob) {
    int row = blockIdx.x, tid = threadIdx.x;
    size_t base = (size_t)row * 1024 + tid * 4;
    float4 x = *(const float4*)(in1 + base);
    if constexpr (MODE & 1) {
        float4 x2 = *(const float4*)(in2 + base);
        x.x += x2.x; x.y += x2.y; x.z += x2.z; x.w += x2.w;
    }
    float s1 = x.x + x.y + x.z + x.w;
    float s2 = x.x * x.x + x.y * x.y + x.z * x.z + x.w * x.w;
#pragma unroll
    for (int m = 32; m >= 1; m >>= 1) { s1 += __shfl_xor(s1, m); s2 += __shfl_xor(s2, m); }
    __shared__ float r1[4], r2[4];
    int lane = tid & 63, w = tid >> 6;
    if (lane == 0) { r1[w] = s1; r2[w] = s2; }
    __syncthreads();
    s1 = r1[0] + r1[1] + r1[2] + r1[3];
    s2 = r2[0] + r2[1] + r2[2] + r2[3];
    float mean = s1 * (1.0f / 1024.0f);
    float var = s2 * (1.0f / 1024.0f) - mean * mean;
    float rstd = rsqrtf(var + 1e-5f);
    float4 gv = *(const float4*)(gg + tid * 4);
    float4 bv = *(const float4*)(bb + tid * 4);
    float y0 = (x.x - mean) * rstd * gv.x + bv.x;
    float y1 = (x.y - mean) * rstd * gv.y + bv.y;
    float y2 = (x.z - mean) * rstd * gv.z + bv.z;
    float y3 = (x.w - mean) * rstd * gv.w + bv.w;
    if constexpr (MODE & 2) {
        float o0 = y0, o1 = y1, o2 = y2, o3 = y3;
        if constexpr (MODE & 8) {
            float4 p = *(const float4*)(post + base);
            o0 += p.x; o1 += p.y; o2 += p.z; o3 += p.w;
        }
        float4 o; o.x = o0; o.y = o1; o.z = o2; o.w = o3;
        *(float4*)(of + base) = o;
    }
    if constexpr (MODE & 4) {
        uint2 pk;
        pk.x = (u32)f2b(y0) | ((u32)f2b(y1) << 16);
        pk.y = (u32)f2b(y2) | ((u32)f2b(y3) << 16);
        *(uint2*)(ob + base) = pk;
    }
}

// ---------------- bf16 GEMM: C[8192,1024] = A[8192,1024] @ WT[1024,1024]^T + bias ----------------
// EPI: 0 = bias -> bf16 ; 1 = bias+relu -> bf16 ; 2 = bias+res -> f32 ; 3 = bias -> f32
template <int EPI>
__global__ __launch_bounds__(256) void gemm_k(const u16* __restrict__ A, const u16* __restrict__ WT,
                                              const float* __restrict__ bias, const float* __restrict__ res,
                                              void* __restrict__ outp) {
    const int N = 1024, K = 1024;
    __shared__ u16 aL[128][40];   // +8 pad: frag reads <=2-way bank conflict
    __shared__ u16 bL[128][40];
    int id = blockIdx.x;
    int swz = (id & 7) * 64 + (id >> 3);   // XCD-contiguous remap (512 % 8 == 0, bijective)
    int bm = swz >> 3, bn = swz & 7;
    const int m0 = bm * 128, n0 = bn * 128;
    int tid = threadIdx.x, lane = tid & 63, w = tid >> 6;
    int wm = w >> 1, wn = w & 1;
    int col = lane & 15, g = lane >> 4;
    int r0 = tid >> 2, cg = tid & 3;
    const u16* Ap = A + (size_t)(m0 + r0) * K + cg * 8;
    const u16* Bp = WT + (size_t)(n0 + r0) * K + cg * 8;
    f32x4 acc[4][4];
#pragma unroll
    for (int m = 0; m < 4; m++)
#pragma unroll
        for (int n = 0; n < 4; n++) acc[m][n] = (f32x4){0.f, 0.f, 0.f, 0.f};

    for (int kt = 0; kt < 32; ++kt) {
        int k0 = kt * 32;
        // prefetch before barrier: overlaps previous iteration's MFMAs
        uint4 a0 = *(const uint4*)(Ap + k0);
        uint4 a1 = *(const uint4*)(Ap + (size_t)64 * K + k0);
        uint4 b0 = *(const uint4*)(Bp + k0);
        uint4 b1 = *(const uint4*)(Bp + (size_t)64 * K + k0);
        __syncthreads();
        *(uint4*)&aL[r0][cg * 8] = a0;
        *(uint4*)&aL[64 + r0][cg * 8] = a1;
        *(uint4*)&bL[r0][cg * 8] = b0;
        *(uint4*)&bL[64 + r0][cg * 8] = b1;
        __syncthreads();
        bf16x8 af[4], bfv[4];
#pragma unroll
        for (int m = 0; m < 4; m++) af[m] = *(const bf16x8*)&aL[wm * 64 + m * 16 + col][g * 8];
#pragma unroll
        for (int n = 0; n < 4; n++) bfv[n] = *(const bf16x8*)&bL[wn * 64 + n * 16 + col][g * 8];
#pragma unroll
        for (int m = 0; m < 4; m++)
#pragma unroll
            for (int n = 0; n < 4; n++) acc[m][n] = MFMA16(af[m], bfv[n], acc[m][n]);
    }
    float bv[4];
#pragma unroll
    for (int n = 0; n < 4; n++) bv[n] = bias[n0 + wn * 64 + n * 16 + col];
#pragma unroll
    for (int m = 0; m < 4; m++) {
#pragma unroll
        for (int r = 0; r < 4; r++) {
            int row = m0 + wm * 64 + m * 16 + g * 4 + r;
#pragma unroll
            for (int n = 0; n < 4; n++) {
                int c = n0 + wn * 64 + n * 16 + col;
                size_t idx = (size_t)row * N + c;
                float v = acc[m][n][r] + bv[n];
                if constexpr (EPI == 0) ((u16*)outp)[idx] = f2b(v);
                else if constexpr (EPI == 1) ((u16*)outp)[idx] = f2b(fmaxf(v, 0.f));
                else if constexpr (EPI == 2) ((float*)outp)[idx] = v + res[idx];
                else ((float*)outp)[idx] = v;
            }
        }
    }
}

// ---------------- flash attention ----------------
// grid (S/64, NH, B), 256 thr. Wave w handles 16 q-rows. K/V read per 64-key tile; V staged
// transposed in LDS; P round-trips per-wave LDS for C->A fragment relayout. O may alias Q.
__global__ __launch_bounds__(256) void attn_k(const u16* __restrict__ Q, const u16* __restrict__ Kc,
                                              const u16* __restrict__ V, const int* __restrict__ mask,
                                              u16* __restrict__ O) {
    const int S = 1024, H = 1024;
    int bq = blockIdx.x, hh = blockIdx.y, bb = blockIdx.z;
    int tid = threadIdx.x, lane = tid & 63, w = tid >> 6;
    int col = lane & 15, g = lane >> 4;
    int q0 = bq * 64 + w * 16;
    __shared__ u16 vt[64][72];       // VT[dh][key]
    __shared__ u16 pl[4][16][72];    // per-wave P[qrow][key]
    size_t qoff = ((size_t)bb * S + q0 + col) * H + hh * 64 + g * 8;
    bf16x8 qa0 = *(const bf16x8*)(Q + qoff);
    bf16x8 qa1 = *(const bf16x8*)(Q + qoff + 32);
    int mneg[4];
#pragma unroll
    for (int r = 0; r < 4; r++) mneg[r] = (mask[bb * S + q0 + g * 4 + r] == 0);
    float mrow[4] = {-1e30f, -1e30f, -1e30f, -1e30f};
    float lrow[4] = {0.f, 0.f, 0.f, 0.f};
    f32x4 oacc[4];
#pragma unroll
    for (int c = 0; c < 4; c++) oacc[c] = (f32x4){0.f, 0.f, 0.f, 0.f};
    const float SCL = 0.125f * 1.44269504088896f;   // 1/sqrt(64) * log2(e)

    for (int kt = 0; kt < 16; ++kt) {
        int kv0 = kt * 64;
        __syncthreads();   // prior tile's vt reads done
#pragma unroll
        for (int it = 0; it < 2; ++it) {
            int dh0 = w * 8 + it * 32;
            union { uint4 u; u16 s[8]; } vv;
            vv.u = *(const uint4*)(V + ((size_t)bb * S + kv0 + lane) * H + hh * 64 + dh0);
#pragma unroll
            for (int i = 0; i < 8; i++) vt[dh0 + i][lane] = vv.s[i];
        }
        __syncthreads();   // vt ready
        f32x4 s[4];
#pragma unroll
        for (int c = 0; c < 4; c++) s[c] = (f32x4){0.f, 0.f, 0.f, 0.f};
#pragma unroll
        for (int c = 0; c < 4; c++) {
            size_t koff = ((size_t)bb * S + kv0 + c * 16 + col) * H + hh * 64 + g * 8;
            bf16x8 k0 = *(const bf16x8*)(Kc + koff);
            bf16x8 k1 = *(const bf16x8*)(Kc + koff + 32);
            s[c] = MFMA16(qa0, k0, s[c]);
            s[c] = MFMA16(qa1, k1, s[c]);
        }
        float p[4][4], pm[4], rs[4], f[4];
#pragma unroll
        for (int r = 0; r < 4; r++)
#pragma unroll
            for (int c = 0; c < 4; c++) {
                float v = s[c][r] * SCL;
                p[c][r] = mneg[r] ? -1e9f : v;   // scaled scores (masked row -> uniform)
            }
#pragma unroll
        for (int r = 0; r < 4; r++) pm[r] = fmaxf(fmaxf(p[0][r], p[1][r]), fmaxf(p[2][r], p[3][r]));
#pragma unroll
        for (int m = 1; m <= 8; m <<= 1)
#pragma unroll
            for (int r = 0; r < 4; r++) pm[r] = fmaxf(pm[r], __shfl_xor(pm[r], m));
#pragma unroll
        for (int r = 0; r < 4; r++) {
            float mn = fmaxf(mrow[r], pm[r]);
            f[r] = exp2f(mrow[r] - mn);
            mrow[r] = mn;
        }
#pragma unroll
        for (int r = 0; r < 4; r++) {
#pragma unroll
            for (int c = 0; c < 4; c++) p[c][r] = exp2f(p[c][r] - mrow[r]);
            rs[r] = p[0][r] + p[1][r] + p[2][r] + p[3][r];
        }
#pragma unroll
        for (int m = 1; m <= 8; m <<= 1)
#pragma unroll
            for (int r = 0; r < 4; r++) rs[r] += __shfl_xor(rs[r], m);
#pragma unroll
        for (int r = 0; r < 4; r++) lrow[r] = lrow[r] * f[r] + rs[r];
#pragma unroll
        for (int c = 0; c < 4; c++)
#pragma unroll
            for (int r = 0; r < 4; r++) oacc[c][r] *= f[r];
        // P: C-layout regs -> per-wave LDS -> A-layout frags
#pragma unroll
        for (int c = 0; c < 4; c++)
#pragma unroll
            for (int r = 0; r < 4; r++) pl[w][g * 4 + r][c * 16 + col] = f2b(p[c][r]);
        asm volatile("s_waitcnt lgkmcnt(0)" ::: "memory");
        bf16x8 pa0 = *(const bf16x8*)&pl[w][col][g * 8];
        bf16x8 pa1 = *(const bf16x8*)&pl[w][col][g * 8 + 32];
#pragma unroll
        for (int c = 0; c < 4; c++) {
            bf16x8 v0 = *(const bf16x8*)&vt[c * 16 + col][g * 8];
            bf16x8 v1 = *(const bf16x8*)&vt[c * 16 + col][g * 8 + 32];
            oacc[c] = MFMA16(pa0, v0, oacc[c]);
            oacc[c] = MFMA16(pa1, v1, oacc[c]);
        }
    }
#pragma unroll
    for (int r = 0; r < 4; r++) {
        float inv = 1.0f / lrow[r];
#pragma unroll
        for (int c = 0; c < 4; c++)
            O[((size_t)bb * S + q0 + g * 4 + r) * H + hh * 64 + c * 16 + col] = f2b(oacc[c][r] * inv);
    }
}

extern "C" void kernel_launch(void* const* d_in, const int* in_sizes, int n_in,
                              void* d_out, int out_size, void* d_ws, size_t ws_size,
                              hipStream_t stream) {
    (void)in_sizes; (void)n_in; (void)out_size; (void)ws_size;
    const float* x = (const float*)d_in[0];
    const float* h = (const float*)d_in[1];
    const int* mask = (const int*)d_in[2];
    const float* W[10];
    const float* Bv[10];
    for (int i = 0; i < 10; i++) { W[i] = (const float*)d_in[3 + i]; Bv[i] = (const float*)d_in[13 + i]; }
    const float *ln1g = (const float*)d_in[23], *ln1b = (const float*)d_in[24];
    const float *ln2g = (const float*)d_in[25], *ln2b = (const float*)d_in[26];
    const float *ln3g = (const float*)d_in[27], *ln3b = (const float*)d_in[28];
    const float *lnhg = (const float*)d_in[29], *lnhb = (const float*)d_in[30];
    const float *flng = (const float*)d_in[31], *flnb = (const float*)d_in[32];

    char* ws = (char*)d_ws;
    size_t off = 0;
    auto alloc = [&](size_t bytes) -> char* {
        char* p = ws + off;
        off += (bytes + 255) & ~(size_t)255;
        return p;
    };
    const size_t MT = (size_t)8192 * 1024;
    u16* wt[10];
    for (int i = 0; i < 10; i++) wt[i] = (u16*)alloc((size_t)1024 * 1024 * 2);
    u16* bufA = (u16*)alloc(MT * 2);   // xn / midn / ybf
    u16* hn   = (u16*)alloc(MT * 2);
    u16* qb   = (u16*)alloc(MT * 2);   // Q, then attention out (safe alias)
    u16* kb   = (u16*)alloc(MT * 2);   // K, later ff1
    u16* vb   = (u16*)alloc(MT * 2);
    float* hid_in  = (float*)alloc(MT * 4);   // hidden_in, later ff2
    float* hid_mid = (float*)alloc(MT * 4);
    float* yf      = (float*)alloc(MT * 4);
    float* outF = (float*)d_out;

    dim3 tb(32, 8), tg(32, 32);
    for (int i = 0; i < 10; i++) tcvt_k<<<tg, tb, 0, stream>>>(W[i], wt[i]);

    // ---- self-attention block ----
    ln_k<4><<<8192, 256, 0, stream>>>(x, nullptr, ln1g, ln1b, nullptr, nullptr, bufA);
    gemm_k<0><<<512, 256, 0, stream>>>(bufA, wt[0], Bv[0], nullptr, qb);
    gemm_k<0><<<512, 256, 0, stream>>>(bufA, wt[1], Bv[1], nullptr, kb);
    gemm_k<0><<<512, 256, 0, stream>>>(bufA, wt[2], Bv[2], nullptr, vb);
    attn_k<<<dim3(16, 16, 8), 256, 0, stream>>>(qb, kb, vb, mask, qb);
    gemm_k<2><<<512, 256, 0, stream>>>(qb, wt[3], Bv[3], x, hid_in);

    // ---- cross-attention block ----
    ln_k<4><<<8192, 256, 0, stream>>>(hid_in, nullptr, ln2g, ln2b, nullptr, nullptr, bufA);
    ln_k<4><<<8192, 256, 0, stream>>>(h, nullptr, lnhg, lnhb, nullptr, nullptr, hn);
    gemm_k<0><<<512, 256, 0, stream>>>(bufA, wt[4], Bv[4], nullptr, qb);
    gemm_k<0><<<512, 256, 0, stream>>>(hn, wt[5], Bv[5], nullptr, kb);
    gemm_k<0><<<512, 256, 0, stream>>>(hn, wt[6], Bv[6], nullptr, vb);
    attn_k<<<dim3(16, 16, 8), 256, 0, stream>>>(qb, kb, vb, mask, qb);
    gemm_k<2><<<512, 256, 0, stream>>>(qb, wt[7], Bv[7], hid_in, hid_mid);

    // ---- FFN block ----
    ln_k<6><<<8192, 256, 0, stream>>>(hid_mid, nullptr, ln3g, ln3b, nullptr, yf, bufA);
    gemm_k<1><<<512, 256, 0, stream>>>(bufA, wt[8], Bv[8], nullptr, kb);   // ff1 = relu(y@w1+b1)
    gemm_k<3><<<512, 256, 0, stream>>>(kb, wt[9], Bv[9], nullptr, hid_in); // ff2
    ln_k<11><<<8192, 256, 0, stream>>>(hid_in, yf, flng, flnb, hid_mid, outF, nullptr);
}

// Round 2
// 550.396 us; speedup vs baseline: 1.3126x; 1.3126x over previous
//
#include <hip/hip_runtime.h>

typedef unsigned short u16;
typedef unsigned int u32;
typedef float f32x4 __attribute__((ext_vector_type(4)));
typedef float f32x16 __attribute__((ext_vector_type(16)));
typedef __bf16 bf16x8 __attribute__((ext_vector_type(8)));

#define MFMA16(a, b, c) __builtin_amdgcn_mfma_f32_16x16x32_bf16(a, b, c, 0, 0, 0)
#define MFMA32(a, b, c) __builtin_amdgcn_mfma_f32_32x32x16_bf16(a, b, c, 0, 0, 0)
#define PLSWAP(x, y) asm volatile("v_permlane32_swap_b32 %0, %1" : "+v"(x), "+v"(y))

__device__ __forceinline__ u16 f2b(float f) {
    u32 u = __builtin_bit_cast(u32, f);
    u += 0x7fffu + ((u >> 16) & 1u);   // round-to-nearest-even
    return (u16)(u >> 16);
}

__device__ __forceinline__ u32 pk2(float a, float b) {
    union { u32 u; __bf16 h[2]; } r;
    r.h[0] = (__bf16)a; r.h[1] = (__bf16)b;
    return r.u;   // compiler emits v_cvt_pk_bf16_f32
}

// ---------------- weight transpose + f32->bf16 convert ----------------
__global__ __launch_bounds__(256) void tcvt_k(const float* __restrict__ Wm, u16* __restrict__ WT) {
    __shared__ float t[32][33];
    int bx = blockIdx.x, by = blockIdx.y;
    int tx = threadIdx.x, ty = threadIdx.y;   // (32,8)
#pragma unroll
    for (int j = 0; j < 32; j += 8)
        t[ty + j][tx] = Wm[(size_t)(by * 32 + ty + j) * 1024 + bx * 32 + tx];
    __syncthreads();
#pragma unroll
    for (int j = 0; j < 32; j += 8)
        WT[(size_t)(bx * 32 + ty + j) * 1024 + by * 32 + tx] = f2b(t[tx][ty + j]);
}

// ---------------- fused LayerNorm ----------------
// MODE bit0: x = in1 + in2 ; bit1: write f32 out (plus bit3: += post) ; bit2: write bf16 out
template <int MODE>
__global__ __launch_bounds__(256) void ln_k(const float* __restrict__ in1, const float* __restrict__ in2,
                                            const float* __restrict__ gg, const float* __restrict__ bb,
                                            const float* __restrict__ post,
                                            float* __restrict__ of, u16* __restrict__ ob) {
    int row = blockIdx.x, tid = threadIdx.x;
    size_t base = (size_t)row * 1024 + tid * 4;
    float4 x = *(const float4*)(in1 + base);
    if constexpr (MODE & 1) {
        float4 x2 = *(const float4*)(in2 + base);
        x.x += x2.x; x.y += x2.y; x.z += x2.z; x.w += x2.w;
    }
    float s1 = x.x + x.y + x.z + x.w;
    float s2 = x.x * x.x + x.y * x.y + x.z * x.z + x.w * x.w;
#pragma unroll
    for (int m = 32; m >= 1; m >>= 1) { s1 += __shfl_xor(s1, m); s2 += __shfl_xor(s2, m); }
    __shared__ float r1[4], r2[4];
    int lane = tid & 63, w = tid >> 6;
    if (lane == 0) { r1[w] = s1; r2[w] = s2; }
    __syncthreads();
    s1 = r1[0] + r1[1] + r1[2] + r1[3];
    s2 = r2[0] + r2[1] + r2[2] + r2[3];
    float mean = s1 * (1.0f / 1024.0f);
    float var = s2 * (1.0f / 1024.0f) - mean * mean;
    float rstd = rsqrtf(var + 1e-5f);
    float4 gv = *(const float4*)(gg + tid * 4);
    float4 bv = *(const float4*)(bb + tid * 4);
    float y0 = (x.x - mean) * rstd * gv.x + bv.x;
    float y1 = (x.y - mean) * rstd * gv.y + bv.y;
    float y2 = (x.z - mean) * rstd * gv.z + bv.z;
    float y3 = (x.w - mean) * rstd * gv.w + bv.w;
    if constexpr (MODE & 2) {
        float o0 = y0, o1 = y1, o2 = y2, o3 = y3;
        if constexpr (MODE & 8) {
            float4 p = *(const float4*)(post + base);
            o0 += p.x; o1 += p.y; o2 += p.z; o3 += p.w;
        }
        float4 o; o.x = o0; o.y = o1; o.z = o2; o.w = o3;
        *(float4*)(of + base) = o;
    }
    if constexpr (MODE & 4) {
        uint2 pk;
        pk.x = (u32)f2b(y0) | ((u32)f2b(y1) << 16);
        pk.y = (u32)f2b(y2) | ((u32)f2b(y3) << 16);
        *(uint2*)(ob + base) = pk;
    }
}

// ---------------- bf16 GEMM (unchanged this round) ----------------
template <int EPI>
__global__ __launch_bounds__(256) void gemm_k(const u16* __restrict__ A, const u16* __restrict__ WT,
                                              const float* __restrict__ bias, const float* __restrict__ res,
                                              void* __restrict__ outp) {
    const int N = 1024, K = 1024;
    __shared__ u16 aL[128][40];
    __shared__ u16 bL[128][40];
    int id = blockIdx.x;
    int swz = (id & 7) * 64 + (id >> 3);
    int bm = swz >> 3, bn = swz & 7;
    const int m0 = bm * 128, n0 = bn * 128;
    int tid = threadIdx.x, lane = tid & 63, w = tid >> 6;
    int wm = w >> 1, wn = w & 1;
    int col = lane & 15, g = lane >> 4;
    int r0 = tid >> 2, cg = tid & 3;
    const u16* Ap = A + (size_t)(m0 + r0) * K + cg * 8;
    const u16* Bp = WT + (size_t)(n0 + r0) * K + cg * 8;
    f32x4 acc[4][4];
#pragma unroll
    for (int m = 0; m < 4; m++)
#pragma unroll
        for (int n = 0; n < 4; n++) acc[m][n] = (f32x4){0.f, 0.f, 0.f, 0.f};

    for (int kt = 0; kt < 32; ++kt) {
        int k0 = kt * 32;
        uint4 a0 = *(const uint4*)(Ap + k0);
        uint4 a1 = *(const uint4*)(Ap + (size_t)64 * K + k0);
        uint4 b0 = *(const uint4*)(Bp + k0);
        uint4 b1 = *(const uint4*)(Bp + (size_t)64 * K + k0);
        __syncthreads();
        *(uint4*)&aL[r0][cg * 8] = a0;
        *(uint4*)&aL[64 + r0][cg * 8] = a1;
        *(uint4*)&bL[r0][cg * 8] = b0;
        *(uint4*)&bL[64 + r0][cg * 8] = b1;
        __syncthreads();
        bf16x8 af[4], bfv[4];
#pragma unroll
        for (int m = 0; m < 4; m++) af[m] = *(const bf16x8*)&aL[wm * 64 + m * 16 + col][g * 8];
#pragma unroll
        for (int n = 0; n < 4; n++) bfv[n] = *(const bf16x8*)&bL[wn * 64 + n * 16 + col][g * 8];
#pragma unroll
        for (int m = 0; m < 4; m++)
#pragma unroll
            for (int n = 0; n < 4; n++) acc[m][n] = MFMA16(af[m], bfv[n], acc[m][n]);
    }
    float bv[4];
#pragma unroll
    for (int n = 0; n < 4; n++) bv[n] = bias[n0 + wn * 64 + n * 16 + col];
#pragma unroll
    for (int m = 0; m < 4; m++) {
#pragma unroll
        for (int r = 0; r < 4; r++) {
            int row = m0 + wm * 64 + m * 16 + g * 4 + r;
#pragma unroll
            for (int n = 0; n < 4; n++) {
                int c = n0 + wn * 64 + n * 16 + col;
                size_t idx = (size_t)row * N + c;
                float v = acc[m][n][r] + bv[n];
                if constexpr (EPI == 0) ((u16*)outp)[idx] = f2b(v);
                else if constexpr (EPI == 1) ((u16*)outp)[idx] = f2b(fmaxf(v, 0.f));
                else if constexpr (EPI == 2) ((float*)outp)[idx] = v + res[idx];
                else ((float*)outp)[idx] = v;
            }
        }
    }
}

// ---------------- flash attention, 32x32 swapped-operand structure ----------------
// grid (S/128, NH, B), 256 thr = 4 waves x 32 q-rows. Per lane: q = lane&31 for S^T, P, O^T
// and softmax state -> all-register softmax, per-lane rescale. KVBLK=64, LDS double-buffered.
__global__ __launch_bounds__(256) void attn_k(const u16* __restrict__ Q, const u16* __restrict__ Kc,
                                              const u16* __restrict__ V, const int* __restrict__ mask,
                                              u16* __restrict__ O) {
    const int S = 1024, H = 1024;
    int bq = blockIdx.x, hh = blockIdx.y, bb = blockIdx.z;
    int tid = threadIdx.x, lane = tid & 63, w = tid >> 6;
    int q = lane & 31, hl = lane >> 5;
    int q0w = bq * 128 + w * 32;

    __shared__ u16 sm[18432];   // 36864 B: [buf][ K 64x72 | V^T 64x72 ]
#define KT(b, r, c) sm[(b) * 9216 + (r) * 72 + (c)]
#define VT(b, r, c) sm[(b) * 9216 + 4608 + (r) * 72 + (c)]

    // Q B-frags (col=q, k=hl*8+j), chunk c covers dh [16c,16c+16)
    const u16* Qrow = Q + ((size_t)bb * S + q0w + q) * H + hh * 64;
    bf16x8 qf[4];
#pragma unroll
    for (int c = 0; c < 4; c++) qf[c] = *(const bf16x8*)(Qrow + c * 16 + hl * 8);
    bool mneg = (mask[bb * S + q0w + q] == 0);

    const float SCLE = 0.18033688f;          // log2(e)/sqrt(64)
    const float THRraw = 8.0f / SCLE;        // defer-max threshold (exp2-domain 8)
    float m = -3e38f, mE = 0.f, mThr = -3e38f, l = 0.f;
    f32x16 oa[2];
#pragma unroll
    for (int i = 0; i < 16; i++) { oa[0][i] = 0.f; oa[1][i] = 0.f; }

    // staging mappings
    int kk = tid >> 2, ks = tid & 3;                 // K: row kk, elems [ks*16, ks*16+16)
    const u16* gK = Kc + ((size_t)bb * S + kk) * H + hh * 64 + ks * 16;
    const u16* gV = V + ((size_t)bb * S + lane) * H + hh * 64 + w * 16;
    uint4 kr0, kr1, vr0, vr1;

#define LOADT(t)                                                   \
    {                                                              \
        const u16* pk_ = gK + (size_t)(t) * 64 * H;                \
        kr0 = *(const uint4*)pk_; kr1 = *(const uint4*)(pk_ + 8);  \
        const u16* pv_ = gV + (size_t)(t) * 64 * H;                \
        vr0 = *(const uint4*)pv_; vr1 = *(const uint4*)(pv_ + 8);  \
    }
#define STORET(bf)                                                   \
    {                                                                \
        *(uint4*)&KT(bf, kk, ks * 16) = kr0;                         \
        *(uint4*)&KT(bf, kk, ks * 16 + 8) = kr1;                     \
        union { uint4 u; u16 s[8]; } va_, vb_;                       \
        va_.u = vr0; vb_.u = vr1;                                    \
        _Pragma("unroll") for (int i_ = 0; i_ < 8; i_++) {           \
            VT(bf, w * 16 + i_, lane) = va_.s[i_];                   \
            VT(bf, w * 16 + 8 + i_, lane) = vb_.s[i_];               \
        }                                                            \
    }

    LOADT(0);
    STORET(0);

    for (int t = 0; t < 16; ++t) {
        int cur = t & 1;
        if (t < 15) LOADT(t + 1);
        __syncthreads();   // buf[cur] ready; prev readers of buf[cur^1] done

        // ---- QK^T: S^T[key][q], 2 subtiles of 32 keys ----
        f32x16 sc[2];
#pragma unroll
        for (int i = 0; i < 16; i++) { sc[0][i] = 0.f; sc[1][i] = 0.f; }
        __builtin_amdgcn_s_setprio(1);
#pragma unroll
        for (int st = 0; st < 2; st++)
#pragma unroll
            for (int c = 0; c < 4; c++) {
                bf16x8 kf = *(const bf16x8*)&KT(cur, st * 32 + q, c * 16 + hl * 8);
                sc[st] = MFMA32(kf, qf[c], sc[st]);
            }
        __builtin_amdgcn_s_setprio(0);

        // ---- softmax (per-lane row), defer-max ----
        float p[32];
#pragma unroll
        for (int st = 0; st < 2; st++)
#pragma unroll
            for (int r = 0; r < 16; r++) p[st * 16 + r] = mneg ? 0.f : sc[st][r];
        float pmax = p[0];
#pragma unroll
        for (int i = 1; i < 32; i++) pmax = fmaxf(pmax, p[i]);
        pmax = fmaxf(pmax, __shfl_xor(pmax, 32));
        if (__any(pmax > mThr)) {
            float mn = fmaxf(m, pmax);
            float f = exp2f((m - mn) * SCLE);
            l *= f;
#pragma unroll
            for (int i = 0; i < 16; i++) { oa[0][i] *= f; oa[1][i] *= f; }
            m = mn; mE = m * SCLE; mThr = m + THRraw;
        }
        float rs = 0.f;
#pragma unroll
        for (int i = 0; i < 32; i++) { p[i] = exp2f(fmaf(p[i], SCLE, -mE)); rs += p[i]; }
        rs += __shfl_xor(rs, 32);
        l += rs;

        // ---- P -> bf16 B-frags via cvt_pk + permlane32_swap; PV: O^T += V^T x P ----
        __builtin_amdgcn_s_setprio(1);
#pragma unroll
        for (int st = 0; st < 2; st++) {
            u32 wv[8];
#pragma unroll
            for (int j = 0; j < 8; j++) wv[j] = pk2(p[st * 16 + 2 * j], p[st * 16 + 2 * j + 1]);
            PLSWAP(wv[0], wv[2]); PLSWAP(wv[1], wv[3]);
            PLSWAP(wv[4], wv[6]); PLSWAP(wv[5], wv[7]);
#pragma unroll
            for (int c = 0; c < 2; c++) {
                union { u32 u[4]; bf16x8 v; } pb;
                pb.u[0] = wv[c * 4 + 0]; pb.u[1] = wv[c * 4 + 1];
                pb.u[2] = wv[c * 4 + 2]; pb.u[3] = wv[c * 4 + 3];
#pragma unroll
                for (int dd = 0; dd < 2; dd++) {
                    bf16x8 vf = *(const bf16x8*)&VT(cur, dd * 32 + q, st * 32 + c * 16 + hl * 8);
                    oa[dd] = MFMA32(vf, pb.v, oa[dd]);
                }
            }
        }
        __builtin_amdgcn_s_setprio(0);

        if (t < 15) STORET(cur ^ 1);
    }

    // ---- epilogue: normalize, transpose O^T -> O via per-wave LDS, coalesced store ----
    __syncthreads();
    float inv = 1.0f / l;
    u16* otw = sm + w * 2304;   // per-wave [32 q][72] bf16
#pragma unroll
    for (int dd = 0; dd < 2; dd++)
#pragma unroll
        for (int r = 0; r < 16; r++) {
            int d = (r & 3) + 8 * (r >> 2) + 4 * hl + 32 * dd;
            otw[q * 72 + d] = f2b(oa[dd][r] * inv);
        }
    __syncthreads();
    size_t obase = ((size_t)bb * S + q0w) * H + hh * 64;
#pragma unroll
    for (int i = 0; i < 4; i++) {
        int row = i * 8 + (lane >> 3);
        uint4 vdat = *(const uint4*)&otw[row * 72 + (lane & 7) * 8];
        *(uint4*)(O + obase + (size_t)row * H + (lane & 7) * 8) = vdat;
    }
#undef KT
#undef VT
#undef LOADT
#undef STORET
}

extern "C" void kernel_launch(void* const* d_in, const int* in_sizes, int n_in,
                              void* d_out, int out_size, void* d_ws, size_t ws_size,
                              hipStream_t stream) {
    (void)in_sizes; (void)n_in; (void)out_size; (void)ws_size;
    const float* x = (const float*)d_in[0];
    const float* h = (const float*)d_in[1];
    const int* mask = (const int*)d_in[2];
    const float* W[10];
    const float* Bv[10];
    for (int i = 0; i < 10; i++) { W[i] = (const float*)d_in[3 + i]; Bv[i] = (const float*)d_in[13 + i]; }
    const float *ln1g = (const float*)d_in[23], *ln1b = (const float*)d_in[24];
    const float *ln2g = (const float*)d_in[25], *ln2b = (const float*)d_in[26];
    const float *ln3g = (const float*)d_in[27], *ln3b = (const float*)d_in[28];
    const float *lnhg = (const float*)d_in[29], *lnhb = (const float*)d_in[30];
    const float *flng = (const float*)d_in[31], *flnb = (const float*)d_in[32];

    char* ws = (char*)d_ws;
    size_t off = 0;
    auto alloc = [&](size_t bytes) -> char* {
        char* p = ws + off;
        off += (bytes + 255) & ~(size_t)255;
        return p;
    };
    const size_t MT = (size_t)8192 * 1024;
    u16* wt[10];
    for (int i = 0; i < 10; i++) wt[i] = (u16*)alloc((size_t)1024 * 1024 * 2);
    u16* bufA = (u16*)alloc(MT * 2);
    u16* hn   = (u16*)alloc(MT * 2);
    u16* qb   = (u16*)alloc(MT * 2);   // Q, then attention out (safe alias)
    u16* kb   = (u16*)alloc(MT * 2);   // K, later ff1
    u16* vb   = (u16*)alloc(MT * 2);
    float* hid_in  = (float*)alloc(MT * 4);
    float* hid_mid = (float*)alloc(MT * 4);
    float* yf      = (float*)alloc(MT * 4);
    float* outF = (float*)d_out;

    dim3 tb(32, 8), tg(32, 32);
    for (int i = 0; i < 10; i++) tcvt_k<<<tg, tb, 0, stream>>>(W[i], wt[i]);

    // ---- self-attention block ----
    ln_k<4><<<8192, 256, 0, stream>>>(x, nullptr, ln1g, ln1b, nullptr, nullptr, bufA);
    gemm_k<0><<<512, 256, 0, stream>>>(bufA, wt[0], Bv[0], nullptr, qb);
    gemm_k<0><<<512, 256, 0, stream>>>(bufA, wt[1], Bv[1], nullptr, kb);
    gemm_k<0><<<512, 256, 0, stream>>>(bufA, wt[2], Bv[2], nullptr, vb);
    attn_k<<<dim3(8, 16, 8), 256, 0, stream>>>(qb, kb, vb, mask, qb);
    gemm_k<2><<<512, 256, 0, stream>>>(qb, wt[3], Bv[3], x, hid_in);

    // ---- cross-attention block ----
    ln_k<4><<<8192, 256, 0, stream>>>(hid_in, nullptr, ln2g, ln2b, nullptr, nullptr, bufA);
    ln_k<4><<<8192, 256, 0, stream>>>(h, nullptr, lnhg, lnhb, nullptr, nullptr, hn);
    gemm_k<0><<<512, 256, 0, stream>>>(bufA, wt[4], Bv[4], nullptr, qb);
    gemm_k<0><<<512, 256, 0, stream>>>(hn, wt[5], Bv[5], nullptr, kb);
    gemm_k<0><<<512, 256, 0, stream>>>(hn, wt[6], Bv[6], nullptr, vb);
    attn_k<<<dim3(8, 16, 8), 256, 0, stream>>>(qb, kb, vb, mask, qb);
    gemm_k<2><<<512, 256, 0, stream>>>(qb, wt[7], Bv[7], hid_in, hid_mid);

    // ---- FFN block ----
    ln_k<6><<<8192, 256, 0, stream>>>(hid_mid, nullptr, ln3g, ln3b, nullptr, yf, bufA);
    gemm_k<1><<<512, 256, 0, stream>>>(bufA, wt[8], Bv[8], nullptr, kb);
    gemm_k<3><<<512, 256, 0, stream>>>(kb, wt[9], Bv[9], nullptr, hid_in);
    ln_k<11><<<8192, 256, 0, stream>>>(hid_in, yf, flng, flnb, hid_mid, outF, nullptr);
}

// Round 3
// 529.738 us; speedup vs baseline: 1.3637x; 1.0390x over previous
//
#include <hip/hip_runtime.h>

typedef unsigned short u16;
typedef unsigned int u32;
typedef float f32x4 __attribute__((ext_vector_type(4)));
typedef float f32x16 __attribute__((ext_vector_type(16)));
typedef __bf16 bf16x8 __attribute__((ext_vector_type(8)));

#define MFMA16(a, b, c) __builtin_amdgcn_mfma_f32_16x16x32_bf16(a, b, c, 0, 0, 0)
#define MFMA32(a, b, c) __builtin_amdgcn_mfma_f32_32x32x16_bf16(a, b, c, 0, 0, 0)
#define PLSWAP(x, y) asm volatile("v_permlane32_swap_b32 %0, %1" : "+v"(x), "+v"(y))

__device__ __forceinline__ u16 f2b(float f) {
    u32 u = __builtin_bit_cast(u32, f);
    u += 0x7fffu + ((u >> 16) & 1u);   // round-to-nearest-even
    return (u16)(u >> 16);
}

__device__ __forceinline__ u32 pk2(float a, float b) {
    union { u32 u; __bf16 h[2]; } r;
    r.h[0] = (__bf16)a; r.h[1] = (__bf16)b;
    return r.u;   // v_cvt_pk_bf16_f32
}

__device__ __forceinline__ void gload16(const u16* g, u16* l) {
    __builtin_amdgcn_global_load_lds((const __attribute__((address_space(1))) void*)g,
                                     (__attribute__((address_space(3))) void*)l, 16, 0, 0);
}

// ---------------- weight transpose + f32->bf16 convert (all 10 in one launch) ----------------
struct W10 { const float* p[10]; };
__global__ __launch_bounds__(256) void tcvt_k(W10 wp, u16* __restrict__ WT0) {
    const float* __restrict__ Wm = wp.p[blockIdx.z];
    u16* __restrict__ WT = WT0 + (size_t)blockIdx.z * 1048576;
    __shared__ float t[32][33];
    int bx = blockIdx.x, by = blockIdx.y;
    int tx = threadIdx.x, ty = threadIdx.y;   // (32,8)
#pragma unroll
    for (int j = 0; j < 32; j += 8)
        t[ty + j][tx] = Wm[(size_t)(by * 32 + ty + j) * 1024 + bx * 32 + tx];
    __syncthreads();
#pragma unroll
    for (int j = 0; j < 32; j += 8)
        WT[(size_t)(bx * 32 + ty + j) * 1024 + by * 32 + tx] = f2b(t[tx][ty + j]);
}

// ---------------- fused LayerNorm ----------------
// MODE bit0: x = in1 + in2 ; bit1: write f32 out (bit3: += post) ; bit2: write bf16 out
template <int MODE>
__global__ __launch_bounds__(256) void ln_k(const float* __restrict__ in1, const float* __restrict__ in2,
                                            const float* __restrict__ gg, const float* __restrict__ bb,
                                            const float* __restrict__ post,
                                            float* __restrict__ of, u16* __restrict__ ob) {
    int row = blockIdx.x, tid = threadIdx.x;
    size_t base = (size_t)row * 1024 + tid * 4;
    float4 x = *(const float4*)(in1 + base);
    if constexpr (MODE & 1) {
        float4 x2 = *(const float4*)(in2 + base);
        x.x += x2.x; x.y += x2.y; x.z += x2.z; x.w += x2.w;
    }
    float s1 = x.x + x.y + x.z + x.w;
    float s2 = x.x * x.x + x.y * x.y + x.z * x.z + x.w * x.w;
#pragma unroll
    for (int m = 32; m >= 1; m >>= 1) { s1 += __shfl_xor(s1, m); s2 += __shfl_xor(s2, m); }
    __shared__ float r1[4], r2[4];
    int lane = tid & 63, w = tid >> 6;
    if (lane == 0) { r1[w] = s1; r2[w] = s2; }
    __syncthreads();
    s1 = r1[0] + r1[1] + r1[2] + r1[3];
    s2 = r2[0] + r2[1] + r2[2] + r2[3];
    float mean = s1 * (1.0f / 1024.0f);
    float var = s2 * (1.0f / 1024.0f) - mean * mean;
    float rstd = rsqrtf(var + 1e-5f);
    float4 gv = *(const float4*)(gg + tid * 4);
    float4 bv = *(const float4*)(bb + tid * 4);
    float y0 = (x.x - mean) * rstd * gv.x + bv.x;
    float y1 = (x.y - mean) * rstd * gv.y + bv.y;
    float y2 = (x.z - mean) * rstd * gv.z + bv.z;
    float y3 = (x.w - mean) * rstd * gv.w + bv.w;
    if constexpr (MODE & 2) {
        float o0 = y0, o1 = y1, o2 = y2, o3 = y3;
        if constexpr (MODE & 8) {
            float4 p = *(const float4*)(post + base);
            o0 += p.x; o1 += p.y; o2 += p.z; o3 += p.w;
        }
        float4 o; o.x = o0; o.y = o1; o.z = o2; o.w = o3;
        *(float4*)(of + base) = o;
    }
    if constexpr (MODE & 4) {
        uint2 pk;
        pk.x = (u32)f2b(y0) | ((u32)f2b(y1) << 16);
        pk.y = (u32)f2b(y2) | ((u32)f2b(y3) << 16);
        *(uint2*)(ob + base) = pk;
    }
}

// ---------------- bf16 GEMM, m97 structure: global_load_lds + double-buffered LDS ----------------
// C[8192,1024] = A[8192,1024] @ WT[1024,1024]^T + bias.  BK=32, LDS 2x(8KB A + 8KB B) linear.
// EPI: 0 = bias -> bf16 ; 1 = bias+relu -> bf16 ; 2 = bias+res -> f32 ; 3 = bias -> f32
template <int EPI>
__global__ __launch_bounds__(256, 3) void gemm_k(const u16* __restrict__ A, const u16* __restrict__ WT,
                                                 const float* __restrict__ bias, const float* __restrict__ res,
                                                 void* __restrict__ outp) {
    const int N = 1024, K = 1024;
    __shared__ u16 aL[2][4096];   // [buf][128*32] linear: elem(r,c) at r*32+c
    __shared__ u16 bL[2][4096];
    int id = blockIdx.x;
    int swz = (id & 7) * 64 + (id >> 3);   // XCD-contiguous remap (512 = 8*64, bijective)
    int bm = swz >> 3, bn = swz & 7;
    const int m0 = bm * 128, n0 = bn * 128;
    int tid = threadIdx.x, lane = tid & 63, w = tid >> 6;
    int wm = w >> 1, wn = w & 1;
    int col = lane & 15, g = lane >> 4;
    // staging: wave w instr i lane l -> row w*32 + i*16 + (l>>2), cols [(l&3)*8, +8)
    const u16* Ag = A + (size_t)(m0 + w * 32 + (lane >> 2)) * K + (lane & 3) * 8;
    const u16* Bg = WT + (size_t)(n0 + w * 32 + (lane >> 2)) * K + (lane & 3) * 8;

#define STG(buf, kt)                                                                  \
    {                                                                                 \
        _Pragma("unroll") for (int i_ = 0; i_ < 2; i_++) {                            \
            gload16(Ag + (size_t)(kt) * 32 + i_ * 16 * K, &aL[buf][w * 1024 + i_ * 512]); \
            gload16(Bg + (size_t)(kt) * 32 + i_ * 16 * K, &bL[buf][w * 1024 + i_ * 512]); \
        }                                                                             \
    }

    f32x4 acc[4][4];
#pragma unroll
    for (int m = 0; m < 4; m++)
#pragma unroll
        for (int n = 0; n < 4; n++) acc[m][n] = (f32x4){0.f, 0.f, 0.f, 0.f};

    STG(0, 0);
    __syncthreads();   // drains vmcnt: buf0 ready
#pragma unroll 2
    for (int kt = 0; kt < 32; ++kt) {
        int cur = kt & 1;
        if (kt < 31) STG(cur ^ 1, kt + 1);   // in flight across this step's compute
        bf16x8 af[4], bfv[4];
#pragma unroll
        for (int m = 0; m < 4; m++) af[m] = *(const bf16x8*)&aL[cur][(wm * 64 + m * 16 + col) * 32 + g * 8];
#pragma unroll
        for (int n = 0; n < 4; n++) bfv[n] = *(const bf16x8*)&bL[cur][(wn * 64 + n * 16 + col) * 32 + g * 8];
#pragma unroll
        for (int m = 0; m < 4; m++)
#pragma unroll
            for (int n = 0; n < 4; n++) acc[m][n] = MFMA16(af[m], bfv[n], acc[m][n]);
        __syncthreads();   // next-buf staged complete + this-buf reads done
    }
#undef STG
    float bv[4];
#pragma unroll
    for (int n = 0; n < 4; n++) bv[n] = bias[n0 + wn * 64 + n * 16 + col];
#pragma unroll
    for (int m = 0; m < 4; m++) {
#pragma unroll
        for (int r = 0; r < 4; r++) {
            int row = m0 + wm * 64 + m * 16 + g * 4 + r;
#pragma unroll
            for (int n = 0; n < 4; n++) {
                int c = n0 + wn * 64 + n * 16 + col;
                size_t idx = (size_t)row * N + c;
                float v = acc[m][n][r] + bv[n];
                if constexpr (EPI == 0) ((u16*)outp)[idx] = f2b(v);
                else if constexpr (EPI == 1) ((u16*)outp)[idx] = f2b(fmaxf(v, 0.f));
                else if constexpr (EPI == 2) ((float*)outp)[idx] = v + res[idx];
                else ((float*)outp)[idx] = v;
            }
        }
    }
}

// ---------------- flash attention, 32x32 swapped-operand structure (unchanged) ----------------
__global__ __launch_bounds__(256) void attn_k(const u16* __restrict__ Q, const u16* __restrict__ Kc,
                                              const u16* __restrict__ V, const int* __restrict__ mask,
                                              u16* __restrict__ O) {
    const int S = 1024, H = 1024;
    int bq = blockIdx.x, hh = blockIdx.y, bb = blockIdx.z;
    int tid = threadIdx.x, lane = tid & 63, w = tid >> 6;
    int q = lane & 31, hl = lane >> 5;
    int q0w = bq * 128 + w * 32;

    __shared__ u16 sm[18432];   // 36864 B: [buf][ K 64x72 | V^T 64x72 ]
#define KT(b, r, c) sm[(b) * 9216 + (r) * 72 + (c)]
#define VT(b, r, c) sm[(b) * 9216 + 4608 + (r) * 72 + (c)]

    const u16* Qrow = Q + ((size_t)bb * S + q0w + q) * H + hh * 64;
    bf16x8 qf[4];
#pragma unroll
    for (int c = 0; c < 4; c++) qf[c] = *(const bf16x8*)(Qrow + c * 16 + hl * 8);
    bool mneg = (mask[bb * S + q0w + q] == 0);

    const float SCLE = 0.18033688f;          // log2(e)/sqrt(64)
    const float THRraw = 8.0f / SCLE;
    float m = -3e38f, mE = 0.f, mThr = -3e38f, l = 0.f;
    f32x16 oa[2];
#pragma unroll
    for (int i = 0; i < 16; i++) { oa[0][i] = 0.f; oa[1][i] = 0.f; }

    int kk = tid >> 2, ks = tid & 3;
    const u16* gK = Kc + ((size_t)bb * S + kk) * H + hh * 64 + ks * 16;
    const u16* gV = V + ((size_t)bb * S + lane) * H + hh * 64 + w * 16;
    uint4 kr0, kr1, vr0, vr1;

#define LOADT(t)                                                   \
    {                                                              \
        const u16* pk_ = gK + (size_t)(t) * 64 * H;                \
        kr0 = *(const uint4*)pk_; kr1 = *(const uint4*)(pk_ + 8);  \
        const u16* pv_ = gV + (size_t)(t) * 64 * H;                \
        vr0 = *(const uint4*)pv_; vr1 = *(const uint4*)(pv_ + 8);  \
    }
#define STORET(bf)                                                   \
    {                                                                \
        *(uint4*)&KT(bf, kk, ks * 16) = kr0;                         \
        *(uint4*)&KT(bf, kk, ks * 16 + 8) = kr1;                     \
        union { uint4 u; u16 s[8]; } va_, vb_;                       \
        va_.u = vr0; vb_.u = vr1;                                    \
        _Pragma("unroll") for (int i_ = 0; i_ < 8; i_++) {           \
            VT(bf, w * 16 + i_, lane) = va_.s[i_];                   \
            VT(bf, w * 16 + 8 + i_, lane) = vb_.s[i_];               \
        }                                                            \
    }

    LOADT(0);
    STORET(0);

    for (int t = 0; t < 16; ++t) {
        int cur = t & 1;
        if (t < 15) LOADT(t + 1);
        __syncthreads();

        f32x16 sc[2];
#pragma unroll
        for (int i = 0; i < 16; i++) { sc[0][i] = 0.f; sc[1][i] = 0.f; }
        __builtin_amdgcn_s_setprio(1);
#pragma unroll
        for (int st = 0; st < 2; st++)
#pragma unroll
            for (int c = 0; c < 4; c++) {
                bf16x8 kf = *(const bf16x8*)&KT(cur, st * 32 + q, c * 16 + hl * 8);
                sc[st] = MFMA32(kf, qf[c], sc[st]);
            }
        __builtin_amdgcn_s_setprio(0);

        float p[32];
#pragma unroll
        for (int st = 0; st < 2; st++)
#pragma unroll
            for (int r = 0; r < 16; r++) p[st * 16 + r] = mneg ? 0.f : sc[st][r];
        float pmax = p[0];
#pragma unroll
        for (int i = 1; i < 32; i++) pmax = fmaxf(pmax, p[i]);
        pmax = fmaxf(pmax, __shfl_xor(pmax, 32));
        if (__any(pmax > mThr)) {
            float mn = fmaxf(m, pmax);
            float f = exp2f((m - mn) * SCLE);
            l *= f;
#pragma unroll
            for (int i = 0; i < 16; i++) { oa[0][i] *= f; oa[1][i] *= f; }
            m = mn; mE = m * SCLE; mThr = m + THRraw;
        }
        float rs = 0.f;
#pragma unroll
        for (int i = 0; i < 32; i++) { p[i] = exp2f(fmaf(p[i], SCLE, -mE)); rs += p[i]; }
        rs += __shfl_xor(rs, 32);
        l += rs;

        __builtin_amdgcn_s_setprio(1);
#pragma unroll
        for (int st = 0; st < 2; st++) {
            u32 wv[8];
#pragma unroll
            for (int j = 0; j < 8; j++) wv[j] = pk2(p[st * 16 + 2 * j], p[st * 16 + 2 * j + 1]);
            PLSWAP(wv[0], wv[2]); PLSWAP(wv[1], wv[3]);
            PLSWAP(wv[4], wv[6]); PLSWAP(wv[5], wv[7]);
#pragma unroll
            for (int c = 0; c < 2; c++) {
                union { u32 u[4]; bf16x8 v; } pb;
                pb.u[0] = wv[c * 4 + 0]; pb.u[1] = wv[c * 4 + 1];
                pb.u[2] = wv[c * 4 + 2]; pb.u[3] = wv[c * 4 + 3];
#pragma unroll
                for (int dd = 0; dd < 2; dd++) {
                    bf16x8 vf = *(const bf16x8*)&VT(cur, dd * 32 + q, st * 32 + c * 16 + hl * 8);
                    oa[dd] = MFMA32(vf, pb.v, oa[dd]);
                }
            }
        }
        __builtin_amdgcn_s_setprio(0);

        if (t < 15) STORET(cur ^ 1);
    }

    __syncthreads();
    float inv = 1.0f / l;
    u16* otw = sm + w * 2304;
#pragma unroll
    for (int dd = 0; dd < 2; dd++)
#pragma unroll
        for (int r = 0; r < 16; r++) {
            int d = (r & 3) + 8 * (r >> 2) + 4 * hl + 32 * dd;
            otw[q * 72 + d] = f2b(oa[dd][r] * inv);
        }
    __syncthreads();
    size_t obase = ((size_t)bb * S + q0w) * H + hh * 64;
#pragma unroll
    for (int i = 0; i < 4; i++) {
        int row = i * 8 + (lane >> 3);
        uint4 vdat = *(const uint4*)&otw[row * 72 + (lane & 7) * 8];
        *(uint4*)(O + obase + (size_t)row * H + (lane & 7) * 8) = vdat;
    }
#undef KT
#undef VT
#undef LOADT
#undef STORET
}

extern "C" void kernel_launch(void* const* d_in, const int* in_sizes, int n_in,
                              void* d_out, int out_size, void* d_ws, size_t ws_size,
                              hipStream_t stream) {
    (void)in_sizes; (void)n_in; (void)out_size; (void)ws_size;
    const float* x = (const float*)d_in[0];
    const float* h = (const float*)d_in[1];
    const int* mask = (const int*)d_in[2];
    const float* W[10];
    const float* Bv[10];
    for (int i = 0; i < 10; i++) { W[i] = (const float*)d_in[3 + i]; Bv[i] = (const float*)d_in[13 + i]; }
    const float *ln1g = (const float*)d_in[23], *ln1b = (const float*)d_in[24];
    const float *ln2g = (const float*)d_in[25], *ln2b = (const float*)d_in[26];
    const float *ln3g = (const float*)d_in[27], *ln3b = (const float*)d_in[28];
    const float *lnhg = (const float*)d_in[29], *lnhb = (const float*)d_in[30];
    const float *flng = (const float*)d_in[31], *flnb = (const float*)d_in[32];

    char* ws = (char*)d_ws;
    size_t off = 0;
    auto alloc = [&](size_t bytes) -> char* {
        char* p = ws + off;
        off += (bytes + 255) & ~(size_t)255;
        return p;
    };
    const size_t MT = (size_t)8192 * 1024;
    u16* wt[10];
    for (int i = 0; i < 10; i++) wt[i] = (u16*)alloc((size_t)1024 * 1024 * 2);
    u16* bufA = (u16*)alloc(MT * 2);
    u16* hn   = (u16*)alloc(MT * 2);
    u16* qb   = (u16*)alloc(MT * 2);   // Q, then attention out (safe alias)
    u16* kb   = (u16*)alloc(MT * 2);   // K, later ff1
    u16* vb   = (u16*)alloc(MT * 2);
    float* hid_in  = (float*)alloc(MT * 4);   // hidden_in, later ff2(+y)
    float* hid_mid = (float*)alloc(MT * 4);
    float* yf      = (float*)alloc(MT * 4);
    float* outF = (float*)d_out;

    W10 wp;
    for (int i = 0; i < 10; i++) wp.p[i] = W[i];
    tcvt_k<<<dim3(32, 32, 10), dim3(32, 8), 0, stream>>>(wp, wt[0]);

    // ---- self-attention block ----
    ln_k<4><<<8192, 256, 0, stream>>>(x, nullptr, ln1g, ln1b, nullptr, nullptr, bufA);
    gemm_k<0><<<512, 256, 0, stream>>>(bufA, wt[0], Bv[0], nullptr, qb);
    gemm_k<0><<<512, 256, 0, stream>>>(bufA, wt[1], Bv[1], nullptr, kb);
    gemm_k<0><<<512, 256, 0, stream>>>(bufA, wt[2], Bv[2], nullptr, vb);
    attn_k<<<dim3(8, 16, 8), 256, 0, stream>>>(qb, kb, vb, mask, qb);
    gemm_k<2><<<512, 256, 0, stream>>>(qb, wt[3], Bv[3], x, hid_in);

    // ---- cross-attention block ----
    ln_k<4><<<8192, 256, 0, stream>>>(hid_in, nullptr, ln2g, ln2b, nullptr, nullptr, bufA);
    ln_k<4><<<8192, 256, 0, stream>>>(h, nullptr, lnhg, lnhb, nullptr, nullptr, hn);
    gemm_k<0><<<512, 256, 0, stream>>>(bufA, wt[4], Bv[4], nullptr, qb);
    gemm_k<0><<<512, 256, 0, stream>>>(hn, wt[5], Bv[5], nullptr, kb);
    gemm_k<0><<<512, 256, 0, stream>>>(hn, wt[6], Bv[6], nullptr, vb);
    attn_k<<<dim3(8, 16, 8), 256, 0, stream>>>(qb, kb, vb, mask, qb);
    gemm_k<2><<<512, 256, 0, stream>>>(qb, wt[7], Bv[7], hid_in, hid_mid);

    // ---- FFN block ----
    ln_k<6><<<8192, 256, 0, stream>>>(hid_mid, nullptr, ln3g, ln3b, nullptr, yf, bufA);
    gemm_k<1><<<512, 256, 0, stream>>>(bufA, wt[8], Bv[8], nullptr, kb);      // ff1 = relu(y@w1+b1)
    gemm_k<2><<<512, 256, 0, stream>>>(kb, wt[9], Bv[9], yf, hid_in);          // ff2 + y (residual fused)
    ln_k<10><<<8192, 256, 0, stream>>>(hid_in, nullptr, flng, flnb, hid_mid, outF, nullptr);
}